// Round 1
// baseline (580.466 us; speedup 1.0000x reference)
//
#include <hip/hip_runtime.h>
#include <math.h>

#define N_NODES 50000
#define N_EDGES 800000

// ---------------------------------------------------------------------------
// Degrees: in_deg[dst]++ , out_deg[src]++
// ---------------------------------------------------------------------------
__global__ void degrees_kernel(const int* __restrict__ src, const int* __restrict__ dst,
                               int* __restrict__ in_deg, int* __restrict__ out_deg, int E) {
    int e = blockIdx.x * blockDim.x + threadIdx.x;
    if (e < E) {
        atomicAdd(&in_deg[dst[e]], 1);
        atomicAdd(&out_deg[src[e]], 1);
    }
}

// ---------------------------------------------------------------------------
// 3-kernel exclusive scan of in_deg -> row_start (CSR offsets by dst)
// ---------------------------------------------------------------------------
__global__ void scan_block_kernel(const int* __restrict__ in, int* __restrict__ out,
                                  int* __restrict__ blk_sums, int N) {
    int i = blockIdx.x * 256 + threadIdx.x;
    int v = (i < N) ? in[i] : 0;
    int lane = threadIdx.x & 63;
    int wid = threadIdx.x >> 6;
    int x = v;
#pragma unroll
    for (int off = 1; off < 64; off <<= 1) {
        int t = __shfl_up(x, off);
        if (lane >= off) x += t;
    }
    __shared__ int wsum[4];
    if (lane == 63) wsum[wid] = x;
    __syncthreads();
    int woff = 0;
    for (int w = 0; w < wid; ++w) woff += wsum[w];
    int incl = x + woff;
    if (i < N) out[i] = incl - v;                 // exclusive within block
    if (threadIdx.x == 255) blk_sums[blockIdx.x] = incl;  // block total
}

__global__ void scan_top_kernel(const int* __restrict__ blk_sums, int* __restrict__ blk_offs,
                                int* __restrict__ total_out, int NB) {
    int i = threadIdx.x;                          // single block of 256, NB <= 256
    int v = (i < NB) ? blk_sums[i] : 0;
    int lane = threadIdx.x & 63;
    int wid = threadIdx.x >> 6;
    int x = v;
#pragma unroll
    for (int off = 1; off < 64; off <<= 1) {
        int t = __shfl_up(x, off);
        if (lane >= off) x += t;
    }
    __shared__ int wsum[4];
    if (lane == 63) wsum[wid] = x;
    __syncthreads();
    int woff = 0;
    for (int w = 0; w < wid; ++w) woff += wsum[w];
    int incl = x + woff;
    if (i < NB) blk_offs[i] = incl - v;
    if (threadIdx.x == 255) *total_out = incl;    // row_start[N] = E
}

__global__ void scan_add_kernel(int* __restrict__ row_start, const int* __restrict__ blk_offs, int N) {
    int i = blockIdx.x * 256 + threadIdx.x;
    if (i < N) row_start[i] += blk_offs[blockIdx.x];
}

// ---------------------------------------------------------------------------
// CSR fill: csr_src[row_start[d] + cursor[d]++] = src  (grouped by dst)
// ---------------------------------------------------------------------------
__global__ void csr_fill_kernel(const int* __restrict__ src, const int* __restrict__ dst,
                                const int* __restrict__ row_start, int* __restrict__ cursor,
                                int* __restrict__ csr_src, int E) {
    int e = blockIdx.x * blockDim.x + threadIdx.x;
    if (e < E) {
        int d = dst[e];
        int pos = row_start[d] + atomicAdd(&cursor[d], 1);
        csr_src[pos] = src[e];
    }
}

// ---------------------------------------------------------------------------
// Node features + norms. hs0[v] = [d, d>3, 3/d, d>4] * norm_src[v]
// (norm_src folded into the stored features; 3/0 -> inf matches JAX)
// ---------------------------------------------------------------------------
__global__ void feat_kernel(const int* __restrict__ in_deg, const int* __restrict__ out_deg,
                            float* __restrict__ norm_src, float* __restrict__ norm_dst,
                            float4* __restrict__ hs0, int N) {
    int v = blockIdx.x * blockDim.x + threadIdx.x;
    if (v >= N) return;
    float din = (float)in_deg[v];
    float dout = (float)out_deg[v];
    float ns = 1.0f / sqrtf(fmaxf(dout, 1.0f));
    float nd = 1.0f / sqrtf(fmaxf(din, 1.0f));
    norm_src[v] = ns;
    norm_dst[v] = nd;
    float h1 = din;
    float h2 = (din - 3.0f > 0.0f) ? 1.0f : 0.0f;
    float h3 = 3.0f / din;
    float h4 = (din - 4.0f > 0.0f) ? 1.0f : 0.0f;
    hs0[v] = make_float4(h1 * ns, h2 * ns, h3 * ns, h4 * ns);
}

// ---------------------------------------------------------------------------
// Layer 1: IN=4 -> H=64. One wave per node; lanes split neighbors, butterfly
// reduce the float4 agg, then each lane computes one output feature.
// Output stored pre-scaled by norm_src (input for layer 2).
// ---------------------------------------------------------------------------
__global__ void conv4_kernel(const float4* __restrict__ hs0,
                             const int* __restrict__ row_start,
                             const int* __restrict__ csr_src,
                             const float* __restrict__ norm_src,
                             const float* __restrict__ norm_dst,
                             const float* __restrict__ W, const float* __restrict__ b,
                             float* __restrict__ out, int N) {
    __shared__ float sW[4 * 64];
    __shared__ float sb[64];
    sW[threadIdx.x] = W[threadIdx.x];             // blockDim.x == 256 == 4*64
    if (threadIdx.x < 64) sb[threadIdx.x] = b[threadIdx.x];
    __syncthreads();
    int lane = threadIdx.x & 63;
    int wid = threadIdx.x >> 6;
    int v = blockIdx.x * 4 + wid;
    if (v >= N) return;
    int rs = row_start[v], re = row_start[v + 1];
    float ax = 0.f, ay = 0.f, az = 0.f, aw = 0.f;
    for (int e = rs + lane; e < re; e += 64) {
        float4 f = hs0[csr_src[e]];
        ax += f.x; ay += f.y; az += f.z; aw += f.w;
    }
#pragma unroll
    for (int off = 32; off; off >>= 1) {
        ax += __shfl_xor(ax, off);
        ay += __shfl_xor(ay, off);
        az += __shfl_xor(az, off);
        aw += __shfl_xor(aw, off);
    }
    float nd = norm_dst[v];
    float r = sb[lane] + nd * (ax * sW[lane] + ay * sW[64 + lane] +
                               az * sW[128 + lane] + aw * sW[192 + lane]);
    r = fmaxf(r, 0.0f) * norm_src[v];
    out[(size_t)v * 64 + lane] = r;
}

// ---------------------------------------------------------------------------
// Layers 2-4: H=64 -> H=64. One wave per node, feature-per-lane: each
// neighbor read is one coalesced 256B line. Matvec via __shfl broadcast of
// the agg vector against LDS-staged W. scale_out: multiply by norm_src
// (for layers feeding another conv); layer 4 stores raw h for pooling.
// ---------------------------------------------------------------------------
__global__ void conv64_kernel(const float* __restrict__ hs_in,
                              const int* __restrict__ row_start,
                              const int* __restrict__ csr_src,
                              const float* __restrict__ norm_src,
                              const float* __restrict__ norm_dst,
                              const float* __restrict__ W, const float* __restrict__ b,
                              float* __restrict__ out, int scale_out, int N) {
    __shared__ float sW[64 * 64];
    __shared__ float sb[64];
    for (int i = threadIdx.x; i < 64 * 64; i += 256) sW[i] = W[i];
    if (threadIdx.x < 64) sb[threadIdx.x] = b[threadIdx.x];
    __syncthreads();
    int lane = threadIdx.x & 63;
    int wid = threadIdx.x >> 6;
    int v = blockIdx.x * 4 + wid;
    if (v >= N) return;
    int rs = row_start[v], re = row_start[v + 1];
    float acc = 0.0f;
    for (int e = rs; e < re; ++e) {
        int u = csr_src[e];                        // wave-uniform
        acc += hs_in[(size_t)u * 64 + lane];       // coalesced 256B line
    }
    acc *= norm_dst[v];
    float r = sb[lane];
#pragma unroll
    for (int k = 0; k < 64; ++k) {
        float a = __shfl(acc, k);
        r += a * sW[k * 64 + lane];
    }
    r = fmaxf(r, 0.0f);
    if (scale_out) r *= norm_src[v];
    out[(size_t)v * 64 + lane] = r;
}

// ---------------------------------------------------------------------------
// Pool per graph (graph_ids sorted -> contiguous ranges via binary search),
// mean, dot with Wout, sigmoid.
// ---------------------------------------------------------------------------
__global__ void pool_kernel(const float* __restrict__ h, const int* __restrict__ graph_ids,
                            const float* __restrict__ Wout, const float* __restrict__ bout,
                            float* __restrict__ out, int N) {
    int g = blockIdx.x;
    // lower_bound(g) and lower_bound(g+1) — uniform across the block
    int lo = 0, hi = N;
    while (lo < hi) { int mid = (lo + hi) >> 1; if (graph_ids[mid] < g) lo = mid + 1; else hi = mid; }
    int s = lo;
    hi = N;
    while (lo < hi) { int mid = (lo + hi) >> 1; if (graph_ids[mid] < g + 1) lo = mid + 1; else hi = mid; }
    int e2 = lo;

    int lane = threadIdx.x & 63;
    int wid = threadIdx.x >> 6;
    float acc = 0.0f;
    for (int v = s + wid; v < e2; v += 4) acc += h[(size_t)v * 64 + lane];
    __shared__ float sacc[4][64];
    sacc[wid][lane] = acc;
    __syncthreads();
    if (wid == 0) {
        float total = sacc[0][lane] + sacc[1][lane] + sacc[2][lane] + sacc[3][lane];
        float cnt = (float)(e2 - s);
        float emb = total / cnt;
        float p = emb * Wout[lane];
#pragma unroll
        for (int off = 32; off; off >>= 1) p += __shfl_xor(p, off);
        if (lane == 0) out[g] = 1.0f / (1.0f + expf(-(p + bout[0])));
    }
}

// ---------------------------------------------------------------------------
extern "C" void kernel_launch(void* const* d_in, const int* in_sizes, int n_in,
                              void* d_out, int out_size, void* d_ws, size_t ws_size,
                              hipStream_t stream) {
    const int* src = (const int*)d_in[0];
    const int* dst = (const int*)d_in[1];
    const int* graph_ids = (const int*)d_in[2];
    const float* W1 = (const float*)d_in[3];
    const float* b1 = (const float*)d_in[4];
    const float* W2 = (const float*)d_in[5];
    const float* b2 = (const float*)d_in[6];
    const float* W3 = (const float*)d_in[7];
    const float* b3 = (const float*)d_in[8];
    const float* W4 = (const float*)d_in[9];
    const float* b4 = (const float*)d_in[10];
    const float* Wout = (const float*)d_in[11];
    const float* bout = (const float*)d_in[12];
    float* out = (float*)d_out;

    const int N = N_NODES, E = N_EDGES;
    const int NB = (N + 255) / 256;   // 196

    // Workspace layout (~31 MB). All region sizes are multiples of 16 elems,
    // so float4 alignment holds given 256B-aligned d_ws.
    float* bufA = (float*)d_ws;                 // N*64
    float* bufB = bufA + (size_t)N * 64;        // N*64
    float* hs0  = bufB + (size_t)N * 64;        // N*4
    float* norm_src = hs0 + (size_t)N * 4;      // N
    float* norm_dst = norm_src + N;             // N
    int* csr_src   = (int*)(norm_dst + N);      // E
    int* in_deg    = csr_src + E;               // N
    int* out_deg   = in_deg + N;                // N
    int* cursor    = out_deg + N;               // N
    int* row_start = cursor + N;                // N+1
    int* blk_sums  = row_start + (N + 1);       // NB
    int* blk_offs  = blk_sums + NB;             // NB

    // zero in_deg / out_deg / cursor (contiguous)
    hipMemsetAsync(in_deg, 0, sizeof(int) * (size_t)N * 3, stream);

    degrees_kernel<<<(E + 255) / 256, 256, 0, stream>>>(src, dst, in_deg, out_deg, E);
    scan_block_kernel<<<NB, 256, 0, stream>>>(in_deg, row_start, blk_sums, N);
    scan_top_kernel<<<1, 256, 0, stream>>>(blk_sums, blk_offs, row_start + N, NB);
    scan_add_kernel<<<NB, 256, 0, stream>>>(row_start, blk_offs, N);
    feat_kernel<<<NB, 256, 0, stream>>>(in_deg, out_deg, norm_src, norm_dst, (float4*)hs0, N);
    csr_fill_kernel<<<(E + 255) / 256, 256, 0, stream>>>(src, dst, row_start, cursor, csr_src, E);

    conv4_kernel<<<(N + 3) / 4, 256, 0, stream>>>((const float4*)hs0, row_start, csr_src,
                                                  norm_src, norm_dst, W1, b1, bufA, N);
    conv64_kernel<<<(N + 3) / 4, 256, 0, stream>>>(bufA, row_start, csr_src, norm_src, norm_dst,
                                                   W2, b2, bufB, 1, N);
    conv64_kernel<<<(N + 3) / 4, 256, 0, stream>>>(bufB, row_start, csr_src, norm_src, norm_dst,
                                                   W3, b3, bufA, 1, N);
    conv64_kernel<<<(N + 3) / 4, 256, 0, stream>>>(bufA, row_start, csr_src, norm_src, norm_dst,
                                                   W4, b4, bufB, 0, N);
    pool_kernel<<<64, 256, 0, stream>>>(bufB, graph_ids, Wout, bout, out, N);
}

// Round 2
// 481.715 us; speedup vs baseline: 1.2050x; 1.2050x over previous
//
#include <hip/hip_runtime.h>
#include <math.h>

#define N_NODES 50000
#define N_EDGES 800000

// ---------------- bf16 helpers (RNE) ----------------
__device__ __forceinline__ float bf16_to_f(unsigned short u) {
    union { unsigned int i; float f; } c; c.i = ((unsigned int)u) << 16; return c.f;
}
__device__ __forceinline__ unsigned short f_to_bf16(float f) {
    union { float f; unsigned int i; } c; c.f = f;
    unsigned int x = c.i;
    unsigned int r = x + 0x7fffu + ((x >> 16) & 1u);   // round-to-nearest-even
    return (unsigned short)(r >> 16);
}

// ---------------------------------------------------------------------------
// Degrees: in_deg[dst]++ , out_deg[src]++
// ---------------------------------------------------------------------------
__global__ void degrees_kernel(const int* __restrict__ src, const int* __restrict__ dst,
                               int* __restrict__ in_deg, int* __restrict__ out_deg, int E) {
    int e = blockIdx.x * blockDim.x + threadIdx.x;
    if (e < E) {
        atomicAdd(&in_deg[dst[e]], 1);
        atomicAdd(&out_deg[src[e]], 1);
    }
}

// ---------------------------------------------------------------------------
// 3-kernel exclusive scan of in_deg -> row_start (CSR offsets by dst)
// ---------------------------------------------------------------------------
__global__ void scan_block_kernel(const int* __restrict__ in, int* __restrict__ out,
                                  int* __restrict__ blk_sums, int N) {
    int i = blockIdx.x * 256 + threadIdx.x;
    int v = (i < N) ? in[i] : 0;
    int lane = threadIdx.x & 63;
    int wid = threadIdx.x >> 6;
    int x = v;
#pragma unroll
    for (int off = 1; off < 64; off <<= 1) {
        int t = __shfl_up(x, off);
        if (lane >= off) x += t;
    }
    __shared__ int wsum[4];
    if (lane == 63) wsum[wid] = x;
    __syncthreads();
    int woff = 0;
    for (int w = 0; w < wid; ++w) woff += wsum[w];
    int incl = x + woff;
    if (i < N) out[i] = incl - v;                 // exclusive within block
    if (threadIdx.x == 255) blk_sums[blockIdx.x] = incl;  // block total
}

__global__ void scan_top_kernel(const int* __restrict__ blk_sums, int* __restrict__ blk_offs,
                                int* __restrict__ total_out, int NB) {
    int i = threadIdx.x;                          // single block of 256, NB <= 256
    int v = (i < NB) ? blk_sums[i] : 0;
    int lane = threadIdx.x & 63;
    int wid = threadIdx.x >> 6;
    int x = v;
#pragma unroll
    for (int off = 1; off < 64; off <<= 1) {
        int t = __shfl_up(x, off);
        if (lane >= off) x += t;
    }
    __shared__ int wsum[4];
    if (lane == 63) wsum[wid] = x;
    __syncthreads();
    int woff = 0;
    for (int w = 0; w < wid; ++w) woff += wsum[w];
    int incl = x + woff;
    if (i < NB) blk_offs[i] = incl - v;
    if (threadIdx.x == 255) *total_out = incl;    // row_start[N] = E
}

// Fused: finalize row_start AND compute node features/norms (independent work,
// same grid shape — saves one launch).
__global__ void scan_add_feat_kernel(int* __restrict__ row_start, const int* __restrict__ blk_offs,
                                     const int* __restrict__ in_deg, const int* __restrict__ out_deg,
                                     float* __restrict__ norm_src, float* __restrict__ norm_dst,
                                     float4* __restrict__ hs0, int N) {
    int i = blockIdx.x * 256 + threadIdx.x;
    if (i >= N) return;
    row_start[i] += blk_offs[blockIdx.x];
    float din = (float)in_deg[i];
    float dout = (float)out_deg[i];
    float ns = 1.0f / sqrtf(fmaxf(dout, 1.0f));
    float nd = 1.0f / sqrtf(fmaxf(din, 1.0f));
    norm_src[i] = ns;
    norm_dst[i] = nd;
    float h1 = din;
    float h2 = (din - 3.0f > 0.0f) ? 1.0f : 0.0f;
    float h3 = 3.0f / din;
    float h4 = (din - 4.0f > 0.0f) ? 1.0f : 0.0f;
    hs0[i] = make_float4(h1 * ns, h2 * ns, h3 * ns, h4 * ns);
}

// ---------------------------------------------------------------------------
// CSR fill: csr_src[row_start[d] + cursor[d]++] = src  (grouped by dst)
// ---------------------------------------------------------------------------
__global__ void csr_fill_kernel(const int* __restrict__ src, const int* __restrict__ dst,
                                const int* __restrict__ row_start, int* __restrict__ cursor,
                                int* __restrict__ csr_src, int E) {
    int e = blockIdx.x * blockDim.x + threadIdx.x;
    if (e < E) {
        int d = dst[e];
        int pos = row_start[d] + atomicAdd(&cursor[d], 1);
        csr_src[pos] = src[e];
    }
}

// ---------------------------------------------------------------------------
// Layer 1: IN=4 -> H=64. One wave per node; lanes split neighbors (the
// float4 gather is a single dwordx4 instruction with 64 scattered addrs —
// already max MLP). Output bf16, pre-scaled by norm_src.
// ---------------------------------------------------------------------------
__global__ void conv4_kernel(const float4* __restrict__ hs0,
                             const int* __restrict__ row_start,
                             const int* __restrict__ csr_src,
                             const float* __restrict__ norm_src,
                             const float* __restrict__ norm_dst,
                             const float* __restrict__ W, const float* __restrict__ b,
                             unsigned short* __restrict__ out, int N) {
    __shared__ float sW[4 * 64];
    __shared__ float sb[64];
    sW[threadIdx.x] = W[threadIdx.x];             // blockDim.x == 256 == 4*64
    if (threadIdx.x < 64) sb[threadIdx.x] = b[threadIdx.x];
    __syncthreads();
    int lane = threadIdx.x & 63;
    int wid = threadIdx.x >> 6;
    int v = blockIdx.x * 4 + wid;
    if (v >= N) return;
    int rs = row_start[v], re = row_start[v + 1];
    float ax = 0.f, ay = 0.f, az = 0.f, aw = 0.f;
    for (int e = rs + lane; e < re; e += 64) {
        float4 f = hs0[csr_src[e]];
        ax += f.x; ay += f.y; az += f.z; aw += f.w;
    }
#pragma unroll
    for (int off = 32; off; off >>= 1) {
        ax += __shfl_xor(ax, off);
        ay += __shfl_xor(ay, off);
        az += __shfl_xor(az, off);
        aw += __shfl_xor(aw, off);
    }
    float nd = norm_dst[v];
    float r = sb[lane] + nd * (ax * sW[lane] + ay * sW[64 + lane] +
                               az * sW[128 + lane] + aw * sW[192 + lane]);
    r = fmaxf(r, 0.0f) * norm_src[v];
    out[(size_t)v * 64 + lane] = f_to_bf16(r);
}

// ---------------------------------------------------------------------------
// Layers 2-4: H=64 -> H=64, bf16 features. One wave per node, feature-per-
// lane. Neighbor indices are loaded cooperatively (one coalesced read per 64
// neighbors) and broadcast via shfl; feature gathers are issued in batches
// of 8 independent loads to maximize memory-level parallelism.
// ---------------------------------------------------------------------------
__global__ void conv64_kernel(const unsigned short* __restrict__ hs_in,
                              const int* __restrict__ row_start,
                              const int* __restrict__ csr_src,
                              const float* __restrict__ norm_src,
                              const float* __restrict__ norm_dst,
                              const float* __restrict__ W, const float* __restrict__ b,
                              unsigned short* __restrict__ out, int scale_out, int N) {
    __shared__ float sW[64 * 64];
    __shared__ float sb[64];
    for (int i = threadIdx.x; i < 64 * 64; i += 256) sW[i] = W[i];
    if (threadIdx.x < 64) sb[threadIdx.x] = b[threadIdx.x];
    __syncthreads();
    int lane = threadIdx.x & 63;
    int wid = threadIdx.x >> 6;
    int v = blockIdx.x * 4 + wid;
    if (v >= N) return;
    int rs = row_start[v], re = row_start[v + 1];
    float acc = 0.0f;
    for (int base = rs; base < re; base += 64) {
        int cnt = min(64, re - base);
        int myidx = (lane < cnt) ? csr_src[base + lane] : 0;   // coalesced
        int j = 0;
        for (; j + 8 <= cnt; j += 8) {
            int u0 = __shfl(myidx, j + 0);
            int u1 = __shfl(myidx, j + 1);
            int u2 = __shfl(myidx, j + 2);
            int u3 = __shfl(myidx, j + 3);
            int u4 = __shfl(myidx, j + 4);
            int u5 = __shfl(myidx, j + 5);
            int u6 = __shfl(myidx, j + 6);
            int u7 = __shfl(myidx, j + 7);
            float f0 = bf16_to_f(hs_in[(size_t)u0 * 64 + lane]);
            float f1 = bf16_to_f(hs_in[(size_t)u1 * 64 + lane]);
            float f2 = bf16_to_f(hs_in[(size_t)u2 * 64 + lane]);
            float f3 = bf16_to_f(hs_in[(size_t)u3 * 64 + lane]);
            float f4 = bf16_to_f(hs_in[(size_t)u4 * 64 + lane]);
            float f5 = bf16_to_f(hs_in[(size_t)u5 * 64 + lane]);
            float f6 = bf16_to_f(hs_in[(size_t)u6 * 64 + lane]);
            float f7 = bf16_to_f(hs_in[(size_t)u7 * 64 + lane]);
            acc += ((f0 + f1) + (f2 + f3)) + ((f4 + f5) + (f6 + f7));
        }
        for (; j < cnt; ++j) {
            int u = __shfl(myidx, j);
            acc += bf16_to_f(hs_in[(size_t)u * 64 + lane]);
        }
    }
    acc *= norm_dst[v];
    float r = sb[lane];
#pragma unroll
    for (int k = 0; k < 64; ++k) {
        float a = __shfl(acc, k);
        r += a * sW[k * 64 + lane];
    }
    r = fmaxf(r, 0.0f);
    if (scale_out) r *= norm_src[v];
    out[(size_t)v * 64 + lane] = f_to_bf16(r);
}

// ---------------------------------------------------------------------------
// Pool per graph (graph_ids sorted -> contiguous ranges via binary search),
// mean, dot with Wout, sigmoid.
// ---------------------------------------------------------------------------
__global__ void pool_kernel(const unsigned short* __restrict__ h, const int* __restrict__ graph_ids,
                            const float* __restrict__ Wout, const float* __restrict__ bout,
                            float* __restrict__ out, int N) {
    int g = blockIdx.x;
    int lo = 0, hi = N;
    while (lo < hi) { int mid = (lo + hi) >> 1; if (graph_ids[mid] < g) lo = mid + 1; else hi = mid; }
    int s = lo;
    hi = N;
    while (lo < hi) { int mid = (lo + hi) >> 1; if (graph_ids[mid] < g + 1) lo = mid + 1; else hi = mid; }
    int e2 = lo;

    int lane = threadIdx.x & 63;
    int wid = threadIdx.x >> 6;
    float acc = 0.0f;
    for (int v = s + wid; v < e2; v += 4) acc += bf16_to_f(h[(size_t)v * 64 + lane]);
    __shared__ float sacc[4][64];
    sacc[wid][lane] = acc;
    __syncthreads();
    if (wid == 0) {
        float total = sacc[0][lane] + sacc[1][lane] + sacc[2][lane] + sacc[3][lane];
        float cnt = (float)(e2 - s);
        float emb = total / cnt;
        float p = emb * Wout[lane];
#pragma unroll
        for (int off = 32; off; off >>= 1) p += __shfl_xor(p, off);
        if (lane == 0) out[g] = 1.0f / (1.0f + expf(-(p + bout[0])));
    }
}

// ---------------------------------------------------------------------------
extern "C" void kernel_launch(void* const* d_in, const int* in_sizes, int n_in,
                              void* d_out, int out_size, void* d_ws, size_t ws_size,
                              hipStream_t stream) {
    const int* src = (const int*)d_in[0];
    const int* dst = (const int*)d_in[1];
    const int* graph_ids = (const int*)d_in[2];
    const float* W1 = (const float*)d_in[3];
    const float* b1 = (const float*)d_in[4];
    const float* W2 = (const float*)d_in[5];
    const float* b2 = (const float*)d_in[6];
    const float* W3 = (const float*)d_in[7];
    const float* b3 = (const float*)d_in[8];
    const float* W4 = (const float*)d_in[9];
    const float* b4 = (const float*)d_in[10];
    const float* Wout = (const float*)d_in[11];
    const float* bout = (const float*)d_in[12];
    float* out = (float*)d_out;

    const int N = N_NODES, E = N_EDGES;
    const int NB = (N + 255) / 256;   // 196

    // Workspace layout. bf16 feature buffers (N*64*2 B each = 6.4 MB, offsets
    // stay 16B-aligned given 256B-aligned d_ws).
    unsigned short* bufA = (unsigned short*)d_ws;          // N*64 bf16
    unsigned short* bufB = bufA + (size_t)N * 64;          // N*64 bf16
    float* hs0 = (float*)(bufB + (size_t)N * 64);          // N*4 f32
    float* norm_src = hs0 + (size_t)N * 4;                 // N
    float* norm_dst = norm_src + N;                        // N
    int* csr_src   = (int*)(norm_dst + N);                 // E
    int* in_deg    = csr_src + E;                          // N
    int* out_deg   = in_deg + N;                           // N
    int* cursor    = out_deg + N;                          // N
    int* row_start = cursor + N;                           // N+1
    int* blk_sums  = row_start + (N + 1);                  // NB
    int* blk_offs  = blk_sums + NB;                        // NB

    hipMemsetAsync(in_deg, 0, sizeof(int) * (size_t)N * 3, stream);

    degrees_kernel<<<(E + 255) / 256, 256, 0, stream>>>(src, dst, in_deg, out_deg, E);
    scan_block_kernel<<<NB, 256, 0, stream>>>(in_deg, row_start, blk_sums, N);
    scan_top_kernel<<<1, 256, 0, stream>>>(blk_sums, blk_offs, row_start + N, NB);
    scan_add_feat_kernel<<<NB, 256, 0, stream>>>(row_start, blk_offs, in_deg, out_deg,
                                                 norm_src, norm_dst, (float4*)hs0, N);
    csr_fill_kernel<<<(E + 255) / 256, 256, 0, stream>>>(src, dst, row_start, cursor, csr_src, E);

    conv4_kernel<<<(N + 3) / 4, 256, 0, stream>>>((const float4*)hs0, row_start, csr_src,
                                                  norm_src, norm_dst, W1, b1, bufA, N);
    conv64_kernel<<<(N + 3) / 4, 256, 0, stream>>>(bufA, row_start, csr_src, norm_src, norm_dst,
                                                   W2, b2, bufB, 1, N);
    conv64_kernel<<<(N + 3) / 4, 256, 0, stream>>>(bufB, row_start, csr_src, norm_src, norm_dst,
                                                   W3, b3, bufA, 1, N);
    conv64_kernel<<<(N + 3) / 4, 256, 0, stream>>>(bufA, row_start, csr_src, norm_src, norm_dst,
                                                   W4, b4, bufB, 0, N);
    pool_kernel<<<64, 256, 0, stream>>>(bufB, graph_ids, Wout, bout, out, N);
}

// Round 3
// 460.109 us; speedup vs baseline: 1.2616x; 1.0470x over previous
//
#include <hip/hip_runtime.h>
#include <math.h>

#define N_NODES 50000
#define N_EDGES 800000

typedef _Float16 half8 __attribute__((ext_vector_type(8)));
typedef float floatx4 __attribute__((ext_vector_type(4)));

// ---------------------------------------------------------------------------
// Degrees: in_deg[dst]++ , out_deg[src]++
// ---------------------------------------------------------------------------
__global__ void degrees_kernel(const int* __restrict__ src, const int* __restrict__ dst,
                               int* __restrict__ in_deg, int* __restrict__ out_deg, int E) {
    int e = blockIdx.x * blockDim.x + threadIdx.x;
    if (e < E) {
        atomicAdd(&in_deg[dst[e]], 1);
        atomicAdd(&out_deg[src[e]], 1);
    }
}

// ---------------------------------------------------------------------------
// 3-kernel exclusive scan of in_deg -> row_start (CSR offsets by dst)
// ---------------------------------------------------------------------------
__global__ void scan_block_kernel(const int* __restrict__ in, int* __restrict__ out,
                                  int* __restrict__ blk_sums, int N) {
    int i = blockIdx.x * 256 + threadIdx.x;
    int v = (i < N) ? in[i] : 0;
    int lane = threadIdx.x & 63;
    int wid = threadIdx.x >> 6;
    int x = v;
#pragma unroll
    for (int off = 1; off < 64; off <<= 1) {
        int t = __shfl_up(x, off);
        if (lane >= off) x += t;
    }
    __shared__ int wsum[4];
    if (lane == 63) wsum[wid] = x;
    __syncthreads();
    int woff = 0;
    for (int w = 0; w < wid; ++w) woff += wsum[w];
    int incl = x + woff;
    if (i < N) out[i] = incl - v;
    if (threadIdx.x == 255) blk_sums[blockIdx.x] = incl;
}

__global__ void scan_top_kernel(const int* __restrict__ blk_sums, int* __restrict__ blk_offs,
                                int* __restrict__ total_out, int NB) {
    int i = threadIdx.x;
    int v = (i < NB) ? blk_sums[i] : 0;
    int lane = threadIdx.x & 63;
    int wid = threadIdx.x >> 6;
    int x = v;
#pragma unroll
    for (int off = 1; off < 64; off <<= 1) {
        int t = __shfl_up(x, off);
        if (lane >= off) x += t;
    }
    __shared__ int wsum[4];
    if (lane == 63) wsum[wid] = x;
    __syncthreads();
    int woff = 0;
    for (int w = 0; w < wid; ++w) woff += wsum[w];
    int incl = x + woff;
    if (i < NB) blk_offs[i] = incl - v;
    if (threadIdx.x == 255) *total_out = incl;
}

// Fused: finalize row_start AND node features/norms.
__global__ void scan_add_feat_kernel(int* __restrict__ row_start, const int* __restrict__ blk_offs,
                                     const int* __restrict__ in_deg, const int* __restrict__ out_deg,
                                     float* __restrict__ norm_src, float* __restrict__ norm_dst,
                                     float4* __restrict__ hs0, int N) {
    int i = blockIdx.x * 256 + threadIdx.x;
    if (i >= N) return;
    row_start[i] += blk_offs[blockIdx.x];
    float din = (float)in_deg[i];
    float dout = (float)out_deg[i];
    float ns = 1.0f / sqrtf(fmaxf(dout, 1.0f));
    float nd = 1.0f / sqrtf(fmaxf(din, 1.0f));
    norm_src[i] = ns;
    norm_dst[i] = nd;
    float h1 = din;
    float h2 = (din - 3.0f > 0.0f) ? 1.0f : 0.0f;
    float h3 = 3.0f / din;
    float h4 = (din - 4.0f > 0.0f) ? 1.0f : 0.0f;
    hs0[i] = make_float4(h1 * ns, h2 * ns, h3 * ns, h4 * ns);
}

// ---------------------------------------------------------------------------
// CSR fill: csr_src[row_start[d] + cursor[d]++] = src
// ---------------------------------------------------------------------------
__global__ void csr_fill_kernel(const int* __restrict__ src, const int* __restrict__ dst,
                                const int* __restrict__ row_start, int* __restrict__ cursor,
                                int* __restrict__ csr_src, int E) {
    int e = blockIdx.x * blockDim.x + threadIdx.x;
    if (e < E) {
        int d = dst[e];
        int pos = row_start[d] + atomicAdd(&cursor[d], 1);
        csr_src[pos] = src[e];
    }
}

// ---------------------------------------------------------------------------
// Transpose W2/W3/W4 (f32 [k][n]) -> WT (f16 [n][k]) for MFMA B-operand reads.
// ---------------------------------------------------------------------------
__global__ void wt_build_kernel(const float* __restrict__ W2, const float* __restrict__ W3,
                                const float* __restrict__ W4, _Float16* __restrict__ WT) {
    int i = blockIdx.x * 256 + threadIdx.x;     // 0..12287
    if (i >= 3 * 4096) return;
    int l = i >> 12;
    int r = i & 4095;
    int k = r >> 6, n = r & 63;
    const float* W = (l == 0) ? W2 : (l == 1) ? W3 : W4;
    WT[l * 4096 + n * 64 + k] = (_Float16)W[r];
}

// ---------------------------------------------------------------------------
// Layer 1: IN=4 -> H=64. One wave per node; lanes split neighbors.
// Output f16 table, pre-scaled by norm_src.
// ---------------------------------------------------------------------------
__global__ void conv4_kernel(const float4* __restrict__ hs0,
                             const int* __restrict__ row_start,
                             const int* __restrict__ csr_src,
                             const float* __restrict__ norm_src,
                             const float* __restrict__ norm_dst,
                             const float* __restrict__ W, const float* __restrict__ b,
                             _Float16* __restrict__ out, int N) {
    __shared__ float sW[4 * 64];
    __shared__ float sb[64];
    sW[threadIdx.x] = W[threadIdx.x];
    if (threadIdx.x < 64) sb[threadIdx.x] = b[threadIdx.x];
    __syncthreads();
    int lane = threadIdx.x & 63;
    int wid = threadIdx.x >> 6;
    int v = blockIdx.x * 4 + wid;
    if (v >= N) return;
    int rs = row_start[v], re = row_start[v + 1];
    float ax = 0.f, ay = 0.f, az = 0.f, aw = 0.f;
    for (int e = rs + lane; e < re; e += 64) {
        float4 f = hs0[csr_src[e]];
        ax += f.x; ay += f.y; az += f.z; aw += f.w;
    }
#pragma unroll
    for (int off = 32; off; off >>= 1) {
        ax += __shfl_xor(ax, off);
        ay += __shfl_xor(ay, off);
        az += __shfl_xor(az, off);
        aw += __shfl_xor(aw, off);
    }
    float nd = norm_dst[v];
    float r = sb[lane] + nd * (ax * sW[lane] + ay * sW[64 + lane] +
                               az * sW[128 + lane] + aw * sW[192 + lane]);
    r = fmaxf(r, 0.0f) * norm_src[v];
    out[(size_t)v * 64 + lane] = (_Float16)r;
}

// ---------------------------------------------------------------------------
// Layers 2-4: H=64 -> H=64, f16 features, MFMA matvec.
// Block = 128 threads = 2 independent waves; each wave handles 16 nodes.
// Phase 1: scalar-pipe CSR walk (readfirstlane-uniform => s_loads for row
//   bounds and neighbor indices; gathers are saddr-form coalesced 128B reads,
//   batch 16 for MLP). Aggregate feature-per-lane in f32, scale by norm_dst,
//   write one f16 row per node into padded LDS tile (pitch 72 => 16B-aligned
//   rows, 2-way-max bank aliasing on fragment reads).
// Phase 2: 16x64 @ 64x64 GEMM via 8x mfma_f32_16x16x32_f16. A from LDS
//   (2 ds_read_b128/lane), B from pre-transposed global WT (L2-resident).
// Epilogue: +bias, relu, optional *norm_src, f16 store (C/D layout:
//   col=lane&15, row=quad*4+reg).
// ---------------------------------------------------------------------------
__global__ void conv64_kernel(const _Float16* __restrict__ hs_in,
                              const int* __restrict__ row_start,
                              const int* __restrict__ csr_src,
                              const float* __restrict__ norm_src,
                              const float* __restrict__ norm_dst,
                              const _Float16* __restrict__ WT, const float* __restrict__ b,
                              _Float16* __restrict__ out, int scale_out, int N) {
    __shared__ _Float16 sAgg[2][16][72];
    __shared__ float snorm[2][16];
    const int lane = threadIdx.x & 63;
    const int wavei = __builtin_amdgcn_readfirstlane(threadIdx.x >> 6);
    const int vbase = blockIdx.x * 32 + wavei * 16;

    // ---- Phase 1: aggregate 16 nodes ----
    for (int i = 0; i < 16; ++i) {
        int v = vbase + i;                       // compiler-uniform
        float acc = 0.0f;
        if (v < N) {
            int rs = row_start[v], re = row_start[v + 1];   // s_loads
            int e = rs;
            for (; e + 16 <= re; e += 16) {
                _Float16 t[16];
#pragma unroll
                for (int j = 0; j < 16; ++j)
                    t[j] = hs_in[(size_t)csr_src[e + j] * 64 + lane];
#pragma unroll
                for (int j = 0; j < 16; ++j) acc += (float)t[j];
            }
            for (; e < re; ++e)
                acc += (float)hs_in[(size_t)csr_src[e] * 64 + lane];
            acc *= norm_dst[v];
            if (lane == 0) snorm[wavei][i] = norm_src[v];
        } else {
            if (lane == 0) snorm[wavei][i] = 0.0f;
        }
        sAgg[wavei][i][lane] = (_Float16)acc;
    }
    __syncthreads();

    // ---- Phase 2: GEMM 16x64x64 via MFMA ----
    const int l15 = lane & 15;
    const int quad = lane >> 4;
    const _Float16* aRow = &sAgg[wavei][l15][quad * 8];
    half8 a0 = *(const half8*)(aRow);            // k = quad*8 + j
    half8 a1 = *(const half8*)(aRow + 32);       // k = 32 + quad*8 + j

    floatx4 c[4];
#pragma unroll
    for (int nt = 0; nt < 4; ++nt) c[nt] = (floatx4){0.f, 0.f, 0.f, 0.f};

#pragma unroll
    for (int nt = 0; nt < 4; ++nt) {
        const _Float16* bp = WT + ((size_t)(nt * 16 + l15)) * 64 + quad * 8;
        half8 b0 = *(const half8*)bp;            // B[k=quad*8+j][n]
        half8 b1 = *(const half8*)(bp + 32);
        c[nt] = __builtin_amdgcn_mfma_f32_16x16x32_f16(a0, b0, c[nt], 0, 0, 0);
        c[nt] = __builtin_amdgcn_mfma_f32_16x16x32_f16(a1, b1, c[nt], 0, 0, 0);
    }

    // ---- Epilogue ----
#pragma unroll
    for (int nt = 0; nt < 4; ++nt) {
        float bias = b[nt * 16 + l15];
#pragma unroll
        for (int r = 0; r < 4; ++r) {
            int m = quad * 4 + r;                // C/D: row = quad*4 + reg
            int v = vbase + m;
            if (v < N) {
                float val = c[nt][r] + bias;
                val = fmaxf(val, 0.0f);
                if (scale_out) val *= snorm[wavei][m];
                out[(size_t)v * 64 + nt * 16 + l15] = (_Float16)val;
            }
        }
    }
}

// ---------------------------------------------------------------------------
// Pool per graph, mean, dot Wout, sigmoid.
// ---------------------------------------------------------------------------
__global__ void pool_kernel(const _Float16* __restrict__ h, const int* __restrict__ graph_ids,
                            const float* __restrict__ Wout, const float* __restrict__ bout,
                            float* __restrict__ out, int N) {
    int g = blockIdx.x;
    int lo = 0, hi = N;
    while (lo < hi) { int mid = (lo + hi) >> 1; if (graph_ids[mid] < g) lo = mid + 1; else hi = mid; }
    int s = lo;
    hi = N;
    while (lo < hi) { int mid = (lo + hi) >> 1; if (graph_ids[mid] < g + 1) lo = mid + 1; else hi = mid; }
    int e2 = lo;

    int lane = threadIdx.x & 63;
    int wid = threadIdx.x >> 6;
    float acc = 0.0f;
    for (int v = s + wid; v < e2; v += 4) acc += (float)h[(size_t)v * 64 + lane];
    __shared__ float sacc[4][64];
    sacc[wid][lane] = acc;
    __syncthreads();
    if (wid == 0) {
        float total = sacc[0][lane] + sacc[1][lane] + sacc[2][lane] + sacc[3][lane];
        float cnt = (float)(e2 - s);
        float emb = total / cnt;
        float p = emb * Wout[lane];
#pragma unroll
        for (int off = 32; off; off >>= 1) p += __shfl_xor(p, off);
        if (lane == 0) out[g] = 1.0f / (1.0f + expf(-(p + bout[0])));
    }
}

// ---------------------------------------------------------------------------
extern "C" void kernel_launch(void* const* d_in, const int* in_sizes, int n_in,
                              void* d_out, int out_size, void* d_ws, size_t ws_size,
                              hipStream_t stream) {
    const int* src = (const int*)d_in[0];
    const int* dst = (const int*)d_in[1];
    const int* graph_ids = (const int*)d_in[2];
    const float* W1 = (const float*)d_in[3];
    const float* b1 = (const float*)d_in[4];
    const float* W2 = (const float*)d_in[5];
    const float* b2 = (const float*)d_in[6];
    const float* W3 = (const float*)d_in[7];
    const float* b3 = (const float*)d_in[8];
    const float* W4 = (const float*)d_in[9];
    const float* b4 = (const float*)d_in[10];
    const float* Wout = (const float*)d_in[11];
    const float* bout = (const float*)d_in[12];
    float* out = (float*)d_out;

    const int N = N_NODES, E = N_EDGES;
    const int NB = (N + 255) / 256;   // 196

    // Workspace layout (all 16B-aligned given 256B-aligned d_ws).
    _Float16* bufA = (_Float16*)d_ws;                      // N*64 f16
    _Float16* bufB = bufA + (size_t)N * 64;                // N*64 f16
    _Float16* WT   = bufB + (size_t)N * 64;                // 3*4096 f16
    float* hs0 = (float*)(WT + 3 * 4096);                  // N*4 f32
    float* norm_src = hs0 + (size_t)N * 4;                 // N
    float* norm_dst = norm_src + N;                        // N
    int* csr_src   = (int*)(norm_dst + N);                 // E
    int* in_deg    = csr_src + E;                          // N
    int* out_deg   = in_deg + N;                           // N
    int* cursor    = out_deg + N;                          // N
    int* row_start = cursor + N;                           // N+1
    int* blk_sums  = row_start + (N + 1);                  // NB
    int* blk_offs  = blk_sums + NB;                        // NB

    hipMemsetAsync(in_deg, 0, sizeof(int) * (size_t)N * 3, stream);

    wt_build_kernel<<<48, 256, 0, stream>>>(W2, W3, W4, WT);
    degrees_kernel<<<(E + 255) / 256, 256, 0, stream>>>(src, dst, in_deg, out_deg, E);
    scan_block_kernel<<<NB, 256, 0, stream>>>(in_deg, row_start, blk_sums, N);
    scan_top_kernel<<<1, 256, 0, stream>>>(blk_sums, blk_offs, row_start + N, NB);
    scan_add_feat_kernel<<<NB, 256, 0, stream>>>(row_start, blk_offs, in_deg, out_deg,
                                                 norm_src, norm_dst, (float4*)hs0, N);
    csr_fill_kernel<<<(E + 255) / 256, 256, 0, stream>>>(src, dst, row_start, cursor, csr_src, E);

    conv4_kernel<<<(N + 3) / 4, 256, 0, stream>>>((const float4*)hs0, row_start, csr_src,
                                                  norm_src, norm_dst, W1, b1, bufA, N);
    const int CB = (N + 31) / 32;   // 1563 blocks of 128 threads (2 waves x 16 nodes)
    conv64_kernel<<<CB, 128, 0, stream>>>(bufA, row_start, csr_src, norm_src, norm_dst,
                                          WT + 0 * 4096, b2, bufB, 1, N);
    conv64_kernel<<<CB, 128, 0, stream>>>(bufB, row_start, csr_src, norm_src, norm_dst,
                                          WT + 1 * 4096, b3, bufA, 1, N);
    conv64_kernel<<<CB, 128, 0, stream>>>(bufA, row_start, csr_src, norm_src, norm_dst,
                                          WT + 2 * 4096, b4, bufB, 0, N);
    pool_kernel<<<64, 256, 0, stream>>>(bufB, graph_ids, Wout, bout, out, N);
}

// Round 4
// 434.714 us; speedup vs baseline: 1.3353x; 1.0584x over previous
//
#include <hip/hip_runtime.h>
#include <math.h>

#define N_NODES 50000
#define N_EDGES 800000
#define NP 8                      // node partitions (6250 nodes each)
#define NS 32                     // edge segments (25000 edges each)
#define PSZ (N_NODES / NP)        // 6250
#define SSZ (N_EDGES / NS)        // 25000

typedef _Float16 half8 __attribute__((ext_vector_type(8)));
typedef float floatx4 __attribute__((ext_vector_type(4)));

// ---------------------------------------------------------------------------
// Partitioned LDS histogram: block (p,s) counts in-degree (dst) and
// out-degree (src) for node range p over edge segment s. No global atomics.
// blockIdx = p*NS + s so same-segment blocks are stride-32 apart => same XCD
// (round-robin %8) => segment fetched once from HBM, reused from L2.
// ---------------------------------------------------------------------------
__global__ __launch_bounds__(256) void hist_kernel(const int* __restrict__ src,
                                                   const int* __restrict__ dst,
                                                   unsigned short* __restrict__ inpart,
                                                   unsigned short* __restrict__ outpart) {
    __shared__ int hin[PSZ];
    __shared__ int hout[PSZ];
    int p = blockIdx.x / NS, s = blockIdx.x % NS;
    for (int i = threadIdx.x; i < PSZ; i += 256) { hin[i] = 0; hout[i] = 0; }
    __syncthreads();
    int lo = p * PSZ;
    const int4* d4 = (const int4*)(dst + s * SSZ);
    const int4* s4 = (const int4*)(src + s * SSZ);
    for (int i = threadIdx.x; i < SSZ / 4; i += 256) {
        int4 d = d4[i];
        int4 sv = s4[i];
        int t;
        t = d.x - lo;  if ((unsigned)t < PSZ) atomicAdd(&hin[t], 1);
        t = d.y - lo;  if ((unsigned)t < PSZ) atomicAdd(&hin[t], 1);
        t = d.z - lo;  if ((unsigned)t < PSZ) atomicAdd(&hin[t], 1);
        t = d.w - lo;  if ((unsigned)t < PSZ) atomicAdd(&hin[t], 1);
        t = sv.x - lo; if ((unsigned)t < PSZ) atomicAdd(&hout[t], 1);
        t = sv.y - lo; if ((unsigned)t < PSZ) atomicAdd(&hout[t], 1);
        t = sv.z - lo; if ((unsigned)t < PSZ) atomicAdd(&hout[t], 1);
        t = sv.w - lo; if ((unsigned)t < PSZ) atomicAdd(&hout[t], 1);
    }
    __syncthreads();
    unsigned short* ip = inpart + (size_t)s * N_NODES + lo;
    unsigned short* op = outpart + (size_t)s * N_NODES + lo;
    for (int i = threadIdx.x; i < PSZ; i += 256) {
        ip[i] = (unsigned short)hin[i];
        op[i] = (unsigned short)hout[i];
    }
}

// ---------------------------------------------------------------------------
// Fused: reduce segment partials -> in/out degree, compute node features +
// norms, and do the per-block exclusive scan of in_deg -> row_start.
// ---------------------------------------------------------------------------
__global__ void scan_block_feat_kernel(const unsigned short* __restrict__ inpart,
                                       const unsigned short* __restrict__ outpart,
                                       int* __restrict__ row_start, int* __restrict__ blk_sums,
                                       float* __restrict__ norm_src, float* __restrict__ norm_dst,
                                       float4* __restrict__ hs0, int N) {
    int i = blockIdx.x * 256 + threadIdx.x;
    int din_i = 0, dout_i = 0;
    if (i < N) {
#pragma unroll
        for (int s = 0; s < NS; ++s) {
            din_i += inpart[(size_t)s * N_NODES + i];
            dout_i += outpart[(size_t)s * N_NODES + i];
        }
        float din = (float)din_i;
        float dout = (float)dout_i;
        float ns = 1.0f / sqrtf(fmaxf(dout, 1.0f));
        float nd = 1.0f / sqrtf(fmaxf(din, 1.0f));
        norm_src[i] = ns;
        norm_dst[i] = nd;
        float h1 = din;
        float h2 = (din - 3.0f > 0.0f) ? 1.0f : 0.0f;
        float h3 = 3.0f / din;
        float h4 = (din - 4.0f > 0.0f) ? 1.0f : 0.0f;
        hs0[i] = make_float4(h1 * ns, h2 * ns, h3 * ns, h4 * ns);
    }
    // block-level exclusive scan of din_i
    int lane = threadIdx.x & 63;
    int wid = threadIdx.x >> 6;
    int x = din_i;
#pragma unroll
    for (int off = 1; off < 64; off <<= 1) {
        int t = __shfl_up(x, off);
        if (lane >= off) x += t;
    }
    __shared__ int wsum[4];
    if (lane == 63) wsum[wid] = x;
    __syncthreads();
    int woff = 0;
    for (int w = 0; w < wid; ++w) woff += wsum[w];
    int incl = x + woff;
    if (i < N) row_start[i] = incl - din_i;
    if (threadIdx.x == 255) blk_sums[blockIdx.x] = incl;
}

__global__ void scan_top_kernel(const int* __restrict__ blk_sums, int* __restrict__ blk_offs,
                                int* __restrict__ total_out, int NB) {
    int i = threadIdx.x;
    int v = (i < NB) ? blk_sums[i] : 0;
    int lane = threadIdx.x & 63;
    int wid = threadIdx.x >> 6;
    int x = v;
#pragma unroll
    for (int off = 1; off < 64; off <<= 1) {
        int t = __shfl_up(x, off);
        if (lane >= off) x += t;
    }
    __shared__ int wsum[4];
    if (lane == 63) wsum[wid] = x;
    __syncthreads();
    int woff = 0;
    for (int w = 0; w < wid; ++w) woff += wsum[w];
    int incl = x + woff;
    if (i < NB) blk_offs[i] = incl - v;
    if (threadIdx.x == 255) *total_out = incl;
}

// Finalize row_start and rewrite inpart[s][i] in place into the exclusive
// within-row prefix (count -> offset of segment s inside row i).
__global__ void scan_add_prefix_kernel(int* __restrict__ row_start, const int* __restrict__ blk_offs,
                                       unsigned short* __restrict__ inpart, int N) {
    int i = blockIdx.x * 256 + threadIdx.x;
    if (i >= N) return;
    row_start[i] += blk_offs[blockIdx.x];
    unsigned short run = 0;
#pragma unroll
    for (int s = 0; s < NS; ++s) {
        unsigned short c = inpart[(size_t)s * N_NODES + i];
        inpart[(size_t)s * N_NODES + i] = run;
        run = (unsigned short)(run + c);
    }
}

// ---------------------------------------------------------------------------
// Partitioned CSR fill, LDS cursors, no global atomics.
// pos = row_start[d] + seg_prefix[s][d] + lds_cursor[d]++
// ---------------------------------------------------------------------------
__global__ __launch_bounds__(256) void csr_fill_kernel(const int* __restrict__ src,
                                                       const int* __restrict__ dst,
                                                       const int* __restrict__ row_start,
                                                       const unsigned short* __restrict__ inpart,
                                                       int* __restrict__ csr_src) {
    __shared__ int cur[PSZ];
    int p = blockIdx.x / NS, s = blockIdx.x % NS;
    for (int i = threadIdx.x; i < PSZ; i += 256) cur[i] = 0;
    __syncthreads();
    int lo = p * PSZ;
    int ebase = s * SSZ;
    const unsigned short* pref = inpart + (size_t)s * N_NODES;
    for (int i = threadIdx.x; i < SSZ; i += 256) {
        int d = dst[ebase + i];
        int t = d - lo;
        if ((unsigned)t < PSZ) {
            int r = atomicAdd(&cur[t], 1);
            int pos = row_start[d] + (int)pref[d] + r;
            csr_src[pos] = src[ebase + i];
        }
    }
}

// ---------------------------------------------------------------------------
// Transpose W2/W3/W4 (f32 [k][n]) -> WT (f16 [n][k]) for MFMA B-operand reads.
// ---------------------------------------------------------------------------
__global__ void wt_build_kernel(const float* __restrict__ W2, const float* __restrict__ W3,
                                const float* __restrict__ W4, _Float16* __restrict__ WT) {
    int i = blockIdx.x * 256 + threadIdx.x;     // 0..12287
    if (i >= 3 * 4096) return;
    int l = i >> 12;
    int r = i & 4095;
    int k = r >> 6, n = r & 63;
    const float* W = (l == 0) ? W2 : (l == 1) ? W3 : W4;
    WT[l * 4096 + n * 64 + k] = (_Float16)W[r];
}

// ---------------------------------------------------------------------------
// Layer 1: IN=4 -> H=64. One wave per node; lanes split neighbors.
// Output f16 table, pre-scaled by norm_src.
// ---------------------------------------------------------------------------
__global__ void conv4_kernel(const float4* __restrict__ hs0,
                             const int* __restrict__ row_start,
                             const int* __restrict__ csr_src,
                             const float* __restrict__ norm_src,
                             const float* __restrict__ norm_dst,
                             const float* __restrict__ W, const float* __restrict__ b,
                             _Float16* __restrict__ out, int N) {
    __shared__ float sW[4 * 64];
    __shared__ float sb[64];
    sW[threadIdx.x] = W[threadIdx.x];
    if (threadIdx.x < 64) sb[threadIdx.x] = b[threadIdx.x];
    __syncthreads();
    int lane = threadIdx.x & 63;
    int wid = threadIdx.x >> 6;
    int v = blockIdx.x * 4 + wid;
    if (v >= N) return;
    int rs = row_start[v], re = row_start[v + 1];
    float ax = 0.f, ay = 0.f, az = 0.f, aw = 0.f;
    for (int e = rs + lane; e < re; e += 64) {
        float4 f = hs0[csr_src[e]];
        ax += f.x; ay += f.y; az += f.z; aw += f.w;
    }
#pragma unroll
    for (int off = 32; off; off >>= 1) {
        ax += __shfl_xor(ax, off);
        ay += __shfl_xor(ay, off);
        az += __shfl_xor(az, off);
        aw += __shfl_xor(aw, off);
    }
    float nd = norm_dst[v];
    float r = sb[lane] + nd * (ax * sW[lane] + ay * sW[64 + lane] +
                               az * sW[128 + lane] + aw * sW[192 + lane]);
    r = fmaxf(r, 0.0f) * norm_src[v];
    out[(size_t)v * 64 + lane] = (_Float16)r;
}

// ---------------------------------------------------------------------------
// Layers 2-4: H=64 -> H=64, f16 features, MFMA matvec. (See round-2 notes.)
// ---------------------------------------------------------------------------
__global__ void conv64_kernel(const _Float16* __restrict__ hs_in,
                              const int* __restrict__ row_start,
                              const int* __restrict__ csr_src,
                              const float* __restrict__ norm_src,
                              const float* __restrict__ norm_dst,
                              const _Float16* __restrict__ WT, const float* __restrict__ b,
                              _Float16* __restrict__ out, int scale_out, int N) {
    __shared__ _Float16 sAgg[2][16][72];
    __shared__ float snorm[2][16];
    const int lane = threadIdx.x & 63;
    const int wavei = __builtin_amdgcn_readfirstlane(threadIdx.x >> 6);
    const int vbase = blockIdx.x * 32 + wavei * 16;

    for (int i = 0; i < 16; ++i) {
        int v = vbase + i;
        float acc = 0.0f;
        if (v < N) {
            int rs = row_start[v], re = row_start[v + 1];
            int e = rs;
            for (; e + 16 <= re; e += 16) {
                _Float16 t[16];
#pragma unroll
                for (int j = 0; j < 16; ++j)
                    t[j] = hs_in[(size_t)csr_src[e + j] * 64 + lane];
#pragma unroll
                for (int j = 0; j < 16; ++j) acc += (float)t[j];
            }
            for (; e < re; ++e)
                acc += (float)hs_in[(size_t)csr_src[e] * 64 + lane];
            acc *= norm_dst[v];
            if (lane == 0) snorm[wavei][i] = norm_src[v];
        } else {
            if (lane == 0) snorm[wavei][i] = 0.0f;
        }
        sAgg[wavei][i][lane] = (_Float16)acc;
    }
    __syncthreads();

    const int l15 = lane & 15;
    const int quad = lane >> 4;
    const _Float16* aRow = &sAgg[wavei][l15][quad * 8];
    half8 a0 = *(const half8*)(aRow);
    half8 a1 = *(const half8*)(aRow + 32);

    floatx4 c[4];
#pragma unroll
    for (int nt = 0; nt < 4; ++nt) c[nt] = (floatx4){0.f, 0.f, 0.f, 0.f};

#pragma unroll
    for (int nt = 0; nt < 4; ++nt) {
        const _Float16* bp = WT + ((size_t)(nt * 16 + l15)) * 64 + quad * 8;
        half8 b0 = *(const half8*)bp;
        half8 b1 = *(const half8*)(bp + 32);
        c[nt] = __builtin_amdgcn_mfma_f32_16x16x32_f16(a0, b0, c[nt], 0, 0, 0);
        c[nt] = __builtin_amdgcn_mfma_f32_16x16x32_f16(a1, b1, c[nt], 0, 0, 0);
    }

#pragma unroll
    for (int nt = 0; nt < 4; ++nt) {
        float bias = b[nt * 16 + l15];
#pragma unroll
        for (int r = 0; r < 4; ++r) {
            int m = quad * 4 + r;
            int v = vbase + m;
            if (v < N) {
                float val = c[nt][r] + bias;
                val = fmaxf(val, 0.0f);
                if (scale_out) val *= snorm[wavei][m];
                out[(size_t)v * 64 + nt * 16 + l15] = (_Float16)val;
            }
        }
    }
}

// ---------------------------------------------------------------------------
// Pool per graph, mean, dot Wout, sigmoid.
// ---------------------------------------------------------------------------
__global__ void pool_kernel(const _Float16* __restrict__ h, const int* __restrict__ graph_ids,
                            const float* __restrict__ Wout, const float* __restrict__ bout,
                            float* __restrict__ out, int N) {
    int g = blockIdx.x;
    int lo = 0, hi = N;
    while (lo < hi) { int mid = (lo + hi) >> 1; if (graph_ids[mid] < g) lo = mid + 1; else hi = mid; }
    int s = lo;
    hi = N;
    while (lo < hi) { int mid = (lo + hi) >> 1; if (graph_ids[mid] < g + 1) lo = mid + 1; else hi = mid; }
    int e2 = lo;

    int lane = threadIdx.x & 63;
    int wid = threadIdx.x >> 6;
    float acc = 0.0f;
    for (int v = s + wid; v < e2; v += 4) acc += (float)h[(size_t)v * 64 + lane];
    __shared__ float sacc[4][64];
    sacc[wid][lane] = acc;
    __syncthreads();
    if (wid == 0) {
        float total = sacc[0][lane] + sacc[1][lane] + sacc[2][lane] + sacc[3][lane];
        float cnt = (float)(e2 - s);
        float emb = total / cnt;
        float p = emb * Wout[lane];
#pragma unroll
        for (int off = 32; off; off >>= 1) p += __shfl_xor(p, off);
        if (lane == 0) out[g] = 1.0f / (1.0f + expf(-(p + bout[0])));
    }
}

// ---------------------------------------------------------------------------
extern "C" void kernel_launch(void* const* d_in, const int* in_sizes, int n_in,
                              void* d_out, int out_size, void* d_ws, size_t ws_size,
                              hipStream_t stream) {
    const int* src = (const int*)d_in[0];
    const int* dst = (const int*)d_in[1];
    const int* graph_ids = (const int*)d_in[2];
    const float* W1 = (const float*)d_in[3];
    const float* b1 = (const float*)d_in[4];
    const float* W2 = (const float*)d_in[5];
    const float* b2 = (const float*)d_in[6];
    const float* W3 = (const float*)d_in[7];
    const float* b3 = (const float*)d_in[8];
    const float* W4 = (const float*)d_in[9];
    const float* b4 = (const float*)d_in[10];
    const float* Wout = (const float*)d_in[11];
    const float* bout = (const float*)d_in[12];
    float* out = (float*)d_out;

    const int N = N_NODES, E = N_EDGES;
    const int NB = (N + 255) / 256;   // 196

    // Workspace layout (16B-aligned regions given 256B-aligned d_ws).
    _Float16* bufA = (_Float16*)d_ws;                      // N*64 f16
    _Float16* bufB = bufA + (size_t)N * 64;                // N*64 f16
    _Float16* WT   = bufB + (size_t)N * 64;                // 3*4096 f16
    float* hs0 = (float*)(WT + 3 * 4096);                  // N*4 f32
    float* norm_src = hs0 + (size_t)N * 4;                 // N
    float* norm_dst = norm_src + N;                        // N
    int* csr_src   = (int*)(norm_dst + N);                 // E
    int* row_start = csr_src + E;                          // N+1
    int* blk_sums  = row_start + (N + 1);                  // NB
    int* blk_offs  = blk_sums + NB;                        // NB (pad to even)
    unsigned short* inpart  = (unsigned short*)(blk_offs + NB + 2);  // NS*N
    unsigned short* outpart = inpart + (size_t)NS * N;               // NS*N

    wt_build_kernel<<<48, 256, 0, stream>>>(W2, W3, W4, WT);
    hist_kernel<<<NP * NS, 256, 0, stream>>>(src, dst, inpart, outpart);
    scan_block_feat_kernel<<<NB, 256, 0, stream>>>(inpart, outpart, row_start, blk_sums,
                                                   norm_src, norm_dst, (float4*)hs0, N);
    scan_top_kernel<<<1, 256, 0, stream>>>(blk_sums, blk_offs, row_start + N, NB);
    scan_add_prefix_kernel<<<NB, 256, 0, stream>>>(row_start, blk_offs, inpart, N);
    csr_fill_kernel<<<NP * NS, 256, 0, stream>>>(src, dst, row_start, inpart, csr_src);

    conv4_kernel<<<(N + 3) / 4, 256, 0, stream>>>((const float4*)hs0, row_start, csr_src,
                                                  norm_src, norm_dst, W1, b1, bufA, N);
    const int CB = (N + 31) / 32;   // blocks of 128 threads (2 waves x 16 nodes)
    conv64_kernel<<<CB, 128, 0, stream>>>(bufA, row_start, csr_src, norm_src, norm_dst,
                                          WT + 0 * 4096, b2, bufB, 1, N);
    conv64_kernel<<<CB, 128, 0, stream>>>(bufB, row_start, csr_src, norm_src, norm_dst,
                                          WT + 1 * 4096, b3, bufA, 1, N);
    conv64_kernel<<<CB, 128, 0, stream>>>(bufA, row_start, csr_src, norm_src, norm_dst,
                                          WT + 2 * 4096, b4, bufB, 0, N);
    pool_kernel<<<64, 256, 0, stream>>>(bufB, graph_ids, Wout, bout, out, N);
}

// Round 5
// 337.456 us; speedup vs baseline: 1.7201x; 1.2882x over previous
//
#include <hip/hip_runtime.h>
#include <math.h>

#define N_NODES 50000
#define N_EDGES 800000
#define NP 8                      // node partitions (6250 nodes each)
#define NS 32                     // edge segments (25000 edges each)
#define PSZ (N_NODES / NP)        // 6250
#define SSZ (N_EDGES / NS)        // 25000

typedef _Float16 half8 __attribute__((ext_vector_type(8)));
typedef float floatx4 __attribute__((ext_vector_type(4)));

// ---------------------------------------------------------------------------
// Partitioned LDS histogram (no global atomics). See round-3 notes.
// ---------------------------------------------------------------------------
__global__ __launch_bounds__(256) void hist_kernel(const int* __restrict__ src,
                                                   const int* __restrict__ dst,
                                                   unsigned short* __restrict__ inpart,
                                                   unsigned short* __restrict__ outpart) {
    __shared__ int hin[PSZ];
    __shared__ int hout[PSZ];
    int p = blockIdx.x / NS, s = blockIdx.x % NS;
    for (int i = threadIdx.x; i < PSZ; i += 256) { hin[i] = 0; hout[i] = 0; }
    __syncthreads();
    int lo = p * PSZ;
    const int4* d4 = (const int4*)(dst + s * SSZ);
    const int4* s4 = (const int4*)(src + s * SSZ);
    for (int i = threadIdx.x; i < SSZ / 4; i += 256) {
        int4 d = d4[i];
        int4 sv = s4[i];
        int t;
        t = d.x - lo;  if ((unsigned)t < PSZ) atomicAdd(&hin[t], 1);
        t = d.y - lo;  if ((unsigned)t < PSZ) atomicAdd(&hin[t], 1);
        t = d.z - lo;  if ((unsigned)t < PSZ) atomicAdd(&hin[t], 1);
        t = d.w - lo;  if ((unsigned)t < PSZ) atomicAdd(&hin[t], 1);
        t = sv.x - lo; if ((unsigned)t < PSZ) atomicAdd(&hout[t], 1);
        t = sv.y - lo; if ((unsigned)t < PSZ) atomicAdd(&hout[t], 1);
        t = sv.z - lo; if ((unsigned)t < PSZ) atomicAdd(&hout[t], 1);
        t = sv.w - lo; if ((unsigned)t < PSZ) atomicAdd(&hout[t], 1);
    }
    __syncthreads();
    unsigned short* ip = inpart + (size_t)s * N_NODES + lo;
    unsigned short* op = outpart + (size_t)s * N_NODES + lo;
    for (int i = threadIdx.x; i < PSZ; i += 256) {
        ip[i] = (unsigned short)hin[i];
        op[i] = (unsigned short)hout[i];
    }
}

// ---------------------------------------------------------------------------
// Fused: reduce segment partials -> degrees, features/norms, block scan.
// ---------------------------------------------------------------------------
__global__ void scan_block_feat_kernel(const unsigned short* __restrict__ inpart,
                                       const unsigned short* __restrict__ outpart,
                                       int* __restrict__ row_start, int* __restrict__ blk_sums,
                                       float* __restrict__ norm_src, float* __restrict__ norm_dst,
                                       float4* __restrict__ hs0, int N) {
    int i = blockIdx.x * 256 + threadIdx.x;
    int din_i = 0, dout_i = 0;
    if (i < N) {
#pragma unroll
        for (int s = 0; s < NS; ++s) {
            din_i += inpart[(size_t)s * N_NODES + i];
            dout_i += outpart[(size_t)s * N_NODES + i];
        }
        float din = (float)din_i;
        float dout = (float)dout_i;
        float ns = 1.0f / sqrtf(fmaxf(dout, 1.0f));
        float nd = 1.0f / sqrtf(fmaxf(din, 1.0f));
        norm_src[i] = ns;
        norm_dst[i] = nd;
        float h1 = din;
        float h2 = (din - 3.0f > 0.0f) ? 1.0f : 0.0f;
        float h3 = 3.0f / din;
        float h4 = (din - 4.0f > 0.0f) ? 1.0f : 0.0f;
        hs0[i] = make_float4(h1 * ns, h2 * ns, h3 * ns, h4 * ns);
    }
    int lane = threadIdx.x & 63;
    int wid = threadIdx.x >> 6;
    int x = din_i;
#pragma unroll
    for (int off = 1; off < 64; off <<= 1) {
        int t = __shfl_up(x, off);
        if (lane >= off) x += t;
    }
    __shared__ int wsum[4];
    if (lane == 63) wsum[wid] = x;
    __syncthreads();
    int woff = 0;
    for (int w = 0; w < wid; ++w) woff += wsum[w];
    int incl = x + woff;
    if (i < N) row_start[i] = incl - din_i;
    if (threadIdx.x == 255) blk_sums[blockIdx.x] = incl;
}

__global__ void scan_top_kernel(const int* __restrict__ blk_sums, int* __restrict__ blk_offs,
                                int* __restrict__ total_out, int NB) {
    int i = threadIdx.x;
    int v = (i < NB) ? blk_sums[i] : 0;
    int lane = threadIdx.x & 63;
    int wid = threadIdx.x >> 6;
    int x = v;
#pragma unroll
    for (int off = 1; off < 64; off <<= 1) {
        int t = __shfl_up(x, off);
        if (lane >= off) x += t;
    }
    __shared__ int wsum[4];
    if (lane == 63) wsum[wid] = x;
    __syncthreads();
    int woff = 0;
    for (int w = 0; w < wid; ++w) woff += wsum[w];
    int incl = x + woff;
    if (i < NB) blk_offs[i] = incl - v;
    if (threadIdx.x == 255) *total_out = incl;
}

// Finalize row_start; rewrite inpart[s][i] into within-row segment prefix.
__global__ void scan_add_prefix_kernel(int* __restrict__ row_start, const int* __restrict__ blk_offs,
                                       unsigned short* __restrict__ inpart, int N) {
    int i = blockIdx.x * 256 + threadIdx.x;
    if (i >= N) return;
    row_start[i] += blk_offs[blockIdx.x];
    unsigned short run = 0;
#pragma unroll
    for (int s = 0; s < NS; ++s) {
        unsigned short c = inpart[(size_t)s * N_NODES + i];
        inpart[(size_t)s * N_NODES + i] = run;
        run = (unsigned short)(run + c);
    }
}

// ---------------------------------------------------------------------------
// Partitioned CSR fill, LDS cursors, no global atomics.
// ---------------------------------------------------------------------------
__global__ __launch_bounds__(256) void csr_fill_kernel(const int* __restrict__ src,
                                                       const int* __restrict__ dst,
                                                       const int* __restrict__ row_start,
                                                       const unsigned short* __restrict__ inpart,
                                                       int* __restrict__ csr_src) {
    __shared__ int cur[PSZ];
    int p = blockIdx.x / NS, s = blockIdx.x % NS;
    for (int i = threadIdx.x; i < PSZ; i += 256) cur[i] = 0;
    __syncthreads();
    int lo = p * PSZ;
    int ebase = s * SSZ;
    const unsigned short* pref = inpart + (size_t)s * N_NODES;
    for (int i = threadIdx.x; i < SSZ; i += 256) {
        int d = dst[ebase + i];
        int t = d - lo;
        if ((unsigned)t < PSZ) {
            int r = atomicAdd(&cur[t], 1);
            int pos = row_start[d] + (int)pref[d] + r;
            csr_src[pos] = src[ebase + i];
        }
    }
}

// ---------------------------------------------------------------------------
// Transpose W2/W3/W4 (f32 [k][n]) -> WT (f16 [n][k]).
// ---------------------------------------------------------------------------
__global__ void wt_build_kernel(const float* __restrict__ W2, const float* __restrict__ W3,
                                const float* __restrict__ W4, _Float16* __restrict__ WT) {
    int i = blockIdx.x * 256 + threadIdx.x;
    if (i >= 3 * 4096) return;
    int l = i >> 12;
    int r = i & 4095;
    int k = r >> 6, n = r & 63;
    const float* W = (l == 0) ? W2 : (l == 1) ? W3 : W4;
    WT[l * 4096 + n * 64 + k] = (_Float16)W[r];
}

// ---------------------------------------------------------------------------
// Layer 1: IN=4 -> H=64. One wave per node; lanes split neighbors.
// ---------------------------------------------------------------------------
__global__ void conv4_kernel(const float4* __restrict__ hs0,
                             const int* __restrict__ row_start,
                             const int* __restrict__ csr_src,
                             const float* __restrict__ norm_src,
                             const float* __restrict__ norm_dst,
                             const float* __restrict__ W, const float* __restrict__ b,
                             _Float16* __restrict__ out, int N) {
    __shared__ float sW[4 * 64];
    __shared__ float sb[64];
    sW[threadIdx.x] = W[threadIdx.x];
    if (threadIdx.x < 64) sb[threadIdx.x] = b[threadIdx.x];
    __syncthreads();
    int lane = threadIdx.x & 63;
    int wid = threadIdx.x >> 6;
    int v = blockIdx.x * 4 + wid;
    if (v >= N) return;
    int rs = row_start[v], re = row_start[v + 1];
    float ax = 0.f, ay = 0.f, az = 0.f, aw = 0.f;
    for (int e = rs + lane; e < re; e += 64) {
        float4 f = hs0[csr_src[e]];
        ax += f.x; ay += f.y; az += f.z; aw += f.w;
    }
#pragma unroll
    for (int off = 32; off; off >>= 1) {
        ax += __shfl_xor(ax, off);
        ay += __shfl_xor(ay, off);
        az += __shfl_xor(az, off);
        aw += __shfl_xor(aw, off);
    }
    float nd = norm_dst[v];
    float r = sb[lane] + nd * (ax * sW[lane] + ay * sW[64 + lane] +
                               az * sW[128 + lane] + aw * sW[192 + lane]);
    r = fmaxf(r, 0.0f) * norm_src[v];
    out[(size_t)v * 64 + lane] = (_Float16)r;
}

// ---------------------------------------------------------------------------
// Layers 2-4: H=64 -> H=64. One wave = 8 nodes = one contiguous CSR edge
// range, walked in padded 16-edge batches with a 2-deep software pipeline:
// gathers for batch k+1 and index s_loads for batch k+2 issue before batch k
// is accumulated, keeping ~16-32 gathers in flight per wave. Node boundaries
// via scalar flush-while (row_start lines sit in K$). Padding is safe: after
// the final flush the sentinel bound prevents further flushes and garbage
// adds land in a dead accumulator. MFMA tile rows 8-15 are garbage but the
// epilogue masks m < 8. No __syncthreads: each wave owns its LDS tile.
// ---------------------------------------------------------------------------
#define LOADIDX(IDX, E0)                                                \
    _Pragma("unroll")                                                   \
    for (int j = 0; j < 16; ++j) IDX[j] = csr_src[(E0) + j];

#define GATHER(T, IDX)                                                  \
    _Pragma("unroll")                                                   \
    for (int j = 0; j < 16; ++j) {                                      \
        unsigned uu = (unsigned)IDX[j];                                 \
        if (uu >= (unsigned)N_NODES) uu = 0;                            \
        T[j] = hs_in[(size_t)uu * 64 + lane];                           \
    }

#define ACCUM(T)                                                        \
    _Pragma("unroll")                                                   \
    for (int j = 0; j < 16; ++j) {                                      \
        while (ecur == bound) {                                         \
            sAgg[wavei][cur - vbase][lane] =                            \
                (_Float16)(acc * norm_dst[cur]);                        \
            acc = 0.0f;                                                 \
            ++cur;                                                      \
            bound = (cur < vend) ? row_start[cur + 1] : 0x7fffffff;     \
        }                                                               \
        acc += (float)T[j];                                             \
        ++ecur;                                                         \
    }

__global__ __launch_bounds__(256) void conv64_kernel(
        const _Float16* __restrict__ hs_in,
        const int* __restrict__ row_start,
        const int* __restrict__ csr_src,
        const float* __restrict__ norm_src,
        const float* __restrict__ norm_dst,
        const _Float16* __restrict__ WT, const float* __restrict__ b,
        _Float16* __restrict__ out, int scale_out, int N) {
    __shared__ _Float16 sAgg[4][16][72];
    const int lane = threadIdx.x & 63;
    const int wavei = __builtin_amdgcn_readfirstlane(threadIdx.x >> 6);
    const int vbase = blockIdx.x * 32 + wavei * 8;
    if (vbase >= N) return;                       // no barriers => safe

    // ---- Phase 1: pipelined flat-range aggregation of 8 nodes ----
    const int vend = min(vbase + 8, N);
    const int rs = row_start[vbase];
    const int re = row_start[vend];
    int cur = vbase;
    int bound = row_start[vbase + 1];
    int ecur = rs;
    float acc = 0.0f;
    int nbp = (re - rs + 15) >> 4;                // padded batch count
    int e = rs;
    int idxA[16], idxB[16];
    _Float16 tA[16], tB[16];

    if (nbp > 0) {
        LOADIDX(idxA, e);
        GATHER(tA, idxA);
        LOADIDX(idxB, e + 16);
        int k = 0;
        while (k + 2 <= nbp) {
            GATHER(tB, idxB);                     // batch k+1 gathers in flight
            LOADIDX(idxA, e + 32);                // batch k+2 indices in flight
            ACCUM(tA);                            // consume batch k
            if (k + 2 < nbp) {
                GATHER(tA, idxA);                 // batch k+2 gathers
                LOADIDX(idxB, e + 48);            // batch k+3 indices
            }
            ACCUM(tB);                            // consume batch k+1
            k += 2; e += 32;
        }
        if (k < nbp) { ACCUM(tA); }               // odd tail batch
    }
    while (cur < vend) {                          // flush remaining nodes
        sAgg[wavei][cur - vbase][lane] = (_Float16)(acc * norm_dst[cur]);
        acc = 0.0f;
        ++cur;
    }

    // ---- Phase 2: 16x64x64 GEMM via MFMA (rows 8-15 garbage, masked) ----
    const int l15 = lane & 15;
    const int quad = lane >> 4;
    const _Float16* aRow = &sAgg[wavei][l15][quad * 8];
    half8 a0 = *(const half8*)(aRow);
    half8 a1 = *(const half8*)(aRow + 32);

    floatx4 c[4];
#pragma unroll
    for (int nt = 0; nt < 4; ++nt) c[nt] = (floatx4){0.f, 0.f, 0.f, 0.f};

#pragma unroll
    for (int nt = 0; nt < 4; ++nt) {
        const _Float16* bp = WT + ((size_t)(nt * 16 + l15)) * 64 + quad * 8;
        half8 b0 = *(const half8*)bp;
        half8 b1 = *(const half8*)(bp + 32);
        c[nt] = __builtin_amdgcn_mfma_f32_16x16x32_f16(a0, b0, c[nt], 0, 0, 0);
        c[nt] = __builtin_amdgcn_mfma_f32_16x16x32_f16(a1, b1, c[nt], 0, 0, 0);
    }

#pragma unroll
    for (int nt = 0; nt < 4; ++nt) {
        float bias = b[nt * 16 + l15];
#pragma unroll
        for (int r = 0; r < 4; ++r) {
            int m = quad * 4 + r;
            int v = vbase + m;
            if (m < 8 && v < N) {
                float val = c[nt][r] + bias;
                val = fmaxf(val, 0.0f);
                if (scale_out) val *= norm_src[v];
                out[(size_t)v * 64 + nt * 16 + l15] = (_Float16)val;
            }
        }
    }
}

// ---------------------------------------------------------------------------
// Pool per graph, mean, dot Wout, sigmoid.
// ---------------------------------------------------------------------------
__global__ void pool_kernel(const _Float16* __restrict__ h, const int* __restrict__ graph_ids,
                            const float* __restrict__ Wout, const float* __restrict__ bout,
                            float* __restrict__ out, int N) {
    int g = blockIdx.x;
    int lo = 0, hi = N;
    while (lo < hi) { int mid = (lo + hi) >> 1; if (graph_ids[mid] < g) lo = mid + 1; else hi = mid; }
    int s = lo;
    hi = N;
    while (lo < hi) { int mid = (lo + hi) >> 1; if (graph_ids[mid] < g + 1) lo = mid + 1; else hi = mid; }
    int e2 = lo;

    int lane = threadIdx.x & 63;
    int wid = threadIdx.x >> 6;
    float acc = 0.0f;
    for (int v = s + wid; v < e2; v += 4) acc += (float)h[(size_t)v * 64 + lane];
    __shared__ float sacc[4][64];
    sacc[wid][lane] = acc;
    __syncthreads();
    if (wid == 0) {
        float total = sacc[0][lane] + sacc[1][lane] + sacc[2][lane] + sacc[3][lane];
        float cnt = (float)(e2 - s);
        float emb = total / cnt;
        float p = emb * Wout[lane];
#pragma unroll
        for (int off = 32; off; off >>= 1) p += __shfl_xor(p, off);
        if (lane == 0) out[g] = 1.0f / (1.0f + expf(-(p + bout[0])));
    }
}

// ---------------------------------------------------------------------------
extern "C" void kernel_launch(void* const* d_in, const int* in_sizes, int n_in,
                              void* d_out, int out_size, void* d_ws, size_t ws_size,
                              hipStream_t stream) {
    const int* src = (const int*)d_in[0];
    const int* dst = (const int*)d_in[1];
    const int* graph_ids = (const int*)d_in[2];
    const float* W1 = (const float*)d_in[3];
    const float* b1 = (const float*)d_in[4];
    const float* W2 = (const float*)d_in[5];
    const float* b2 = (const float*)d_in[6];
    const float* W3 = (const float*)d_in[7];
    const float* b3 = (const float*)d_in[8];
    const float* W4 = (const float*)d_in[9];
    const float* b4 = (const float*)d_in[10];
    const float* Wout = (const float*)d_in[11];
    const float* bout = (const float*)d_in[12];
    float* out = (float*)d_out;

    const int N = N_NODES, E = N_EDGES;
    const int NB = (N + 255) / 256;   // 196

    _Float16* bufA = (_Float16*)d_ws;                      // N*64 f16
    _Float16* bufB = bufA + (size_t)N * 64;                // N*64 f16
    _Float16* WT   = bufB + (size_t)N * 64;                // 3*4096 f16
    float* hs0 = (float*)(WT + 3 * 4096);                  // N*4 f32
    float* norm_src = hs0 + (size_t)N * 4;                 // N
    float* norm_dst = norm_src + N;                        // N
    int* csr_src   = (int*)(norm_dst + N);                 // E
    int* row_start = csr_src + E;                          // N+1
    int* blk_sums  = row_start + (N + 1);                  // NB
    int* blk_offs  = blk_sums + NB;                        // NB (pad to even)
    unsigned short* inpart  = (unsigned short*)(blk_offs + NB + 2);  // NS*N
    unsigned short* outpart = inpart + (size_t)NS * N;               // NS*N

    wt_build_kernel<<<48, 256, 0, stream>>>(W2, W3, W4, WT);
    hist_kernel<<<NP * NS, 256, 0, stream>>>(src, dst, inpart, outpart);
    scan_block_feat_kernel<<<NB, 256, 0, stream>>>(inpart, outpart, row_start, blk_sums,
                                                   norm_src, norm_dst, (float4*)hs0, N);
    scan_top_kernel<<<1, 256, 0, stream>>>(blk_sums, blk_offs, row_start + N, NB);
    scan_add_prefix_kernel<<<NB, 256, 0, stream>>>(row_start, blk_offs, inpart, N);
    csr_fill_kernel<<<NP * NS, 256, 0, stream>>>(src, dst, row_start, inpart, csr_src);

    conv4_kernel<<<(N + 3) / 4, 256, 0, stream>>>((const float4*)hs0, row_start, csr_src,
                                                  norm_src, norm_dst, W1, b1, bufA, N);
    const int CB = (N + 31) / 32;   // 256 threads = 4 waves x 8 nodes
    conv64_kernel<<<CB, 256, 0, stream>>>(bufA, row_start, csr_src, norm_src, norm_dst,
                                          WT + 0 * 4096, b2, bufB, 1, N);
    conv64_kernel<<<CB, 256, 0, stream>>>(bufB, row_start, csr_src, norm_src, norm_dst,
                                          WT + 1 * 4096, b3, bufA, 1, N);
    conv64_kernel<<<CB, 256, 0, stream>>>(bufA, row_start, csr_src, norm_src, norm_dst,
                                          WT + 2 * 4096, b4, bufB, 0, N);
    pool_kernel<<<64, 256, 0, stream>>>(bufB, graph_ids, Wout, bout, out, N);
}